// Round 5
// baseline (2791.763 us; speedup 1.0000x reference)
//
#include <hip/hip_runtime.h>
#include <stdint.h>

// Problem constants (fixed by the reference)
#define Bc 4
#define Sc 2048
#define Dc 768
#define Kc 8192
#define NSc 2
#define Mc (Bc*Sc)                      // 8192 tokens
#define EMB_ELEMS ((size_t)Mc*NSc*Dc)   // emb output floats; indices follow
#define TPB 32                          // tokens per block
#define MARGIN 0.125f
#define CAND_MAX 24                     // ring-buffer depth per (t,s)

typedef __attribute__((ext_vector_type(8))) __bf16 bf16x8;
typedef __attribute__((ext_vector_type(4))) float f32x4;
typedef __attribute__((ext_vector_type(4))) unsigned short u16x4;

__device__ __forceinline__ unsigned short f2bf(float f){
  unsigned int u = __float_as_uint(f);
  u += 0x7FFFu + ((u >> 16) & 1u);       // round-to-nearest-even
  return (unsigned short)(u >> 16);
}

// ---------------- K0: convert x,w f32 -> bf16 (into ws) ----------------
__global__ __launch_bounds__(256) void k_convert(const float4* __restrict__ x,
                                                 const float4* __restrict__ w,
                                                 u16x4* __restrict__ xb,
                                                 u16x4* __restrict__ wb){
  int i = blockIdx.x * 256 + threadIdx.x;
  float4 v = x[i];
  u16x4 o;
  o.x = f2bf(v.x); o.y = f2bf(v.y); o.z = f2bf(v.z); o.w = f2bf(v.w);
  xb[i] = o;
  v = w[i];
  o.x = f2bf(v.x); o.y = f2bf(v.y); o.z = f2bf(v.z); o.w = f2bf(v.w);
  wb[i] = o;
}

// ---------------- K1: fully fused GEMM + gumbel-argmax + outputs -------------
// One block per 32 tokens (grid 256 = 1/CU). Logits never reach memory.
//  - A fragments (32 tok x 768 k bf16) in registers: af[24] (96 VGPR).
//  - W tile (32 codes x 768 k, 48 KB) reg-staged one tile ahead (T14 split),
//    ds_write with XOR granule swizzle g^(row&7); swizzled ds_read_b128.
//  - gumbel: 8 scalar f32/lane/tile, issued pre-K-loop, consumed in epilogue.
//  - online candidates: per-(t,s) ring buffer (LDS atomics), shared running
//    max gmI (atomicMax on positive floats; init 4.0 < any final max).
//  - resolve: keepers within MARGIN of max; f64 refine + min-k tie-break
//    (r1-validated). One-hot + emb writes (r1-verbatim pattern).
__global__ __launch_bounds__(256, 1) void k_fused(
    const unsigned short* __restrict__ xb,   // [M][768] bf16
    const unsigned short* __restrict__ wb,   // [K][768] bf16
    const float* __restrict__ gumbel,        // [M][NS][K] f32
    const float* __restrict__ x,             // f32 exact (refine)
    const float* __restrict__ w,             // f32 exact (refine)
    const float* __restrict__ emb_tab,       // [K][768] f32
    float* __restrict__ out_emb,
    float* __restrict__ out_ind)
{
  __shared__ __align__(16) unsigned short Bsb[32 * Dc];   // 48 KB
  __shared__ float candv[TPB][NSc][CAND_MAX];             // 6 KB
  __shared__ int   candc[TPB][NSc][CAND_MAX];             // 6 KB
  __shared__ int   cnt[TPB][NSc];
  __shared__ int   gmI[TPB][NSc];
  __shared__ int   sel[TPB][NSc];

  const int tid  = threadIdx.x;
  const int lane = tid & 63;
  const int wid  = tid >> 6;            // 4 waves: 2 token-groups x 2 col-groups
  const int tg   = wid >> 1;
  const int cg   = wid & 1;
  const int fr   = lane & 15;           // frag row (A) / col (B)
  const int fq   = lane >> 4;           // 0..3, k-run selector & C-row group
  const int fr7  = fr & 7;
  const int t0   = blockIdx.x * TPB;

  if (tid < TPB * NSc) {
    cnt[tid >> 1][tid & 1] = 0;
    gmI[tid >> 1][tid & 1] = __float_as_int(4.0f);   // < any final max (whp)
  }

  // A fragments in registers (row = fr per MFMA A layout, validated)
  bf16x8 af[24];
  {
    const unsigned short* ap = xb + (size_t)(t0 + tg*16 + fr) * Dc + fq*8;
    #pragma unroll
    for (int kt = 0; kt < 24; ++kt)
      af[kt] = *(const bf16x8*)(ap + kt*32);
  }

  // prologue: stage regs for tile 0 (12 x 16B/thread; granule G=i*256+tid)
  float4 stg[12];
  #pragma unroll
  for (int i = 0; i < 12; ++i) {
    const int G = i*256 + tid;
    stg[i] = *(const float4*)(wb + (size_t)(G / 96) * Dc + (G % 96) * 8);
  }

  // gumbel address base: addr(s,r,ht) = grow0 + (r*2+s)*Kc + ht*32
  const size_t grow0 = ((size_t)(t0 + tg*16 + fq*4)) * NSc * Kc + cg*16 + fr;

  float gg[8];   // [s*4+r]

  for (int ht = 0; ht < 256; ++ht) {
    __syncthreads();                     // prev K-loop reads of Bsb done
    // write staged tile (XOR granule swizzle: slot = g ^ (row&7))
    #pragma unroll
    for (int i = 0; i < 12; ++i) {
      const int G = i*256 + tid;
      const int r_ = G / 96, c_ = (G % 96) ^ (r_ & 7);
      *(float4*)&Bsb[r_ * Dc + c_ * 8] = stg[i];
    }
    __syncthreads();                     // tile visible

    // issue gumbel for this tile (consumed after K-loop -> hidden)
    #pragma unroll
    for (int s = 0; s < 2; ++s)
      #pragma unroll
      for (int r = 0; r < 4; ++r)
        gg[s*4 + r] = gumbel[grow0 + (size_t)(r*2 + s) * Kc + ht*32];

    // issue next tile's stage loads (consumed at next top barrier -> hidden)
    if (ht < 255) {
      #pragma unroll
      for (int i = 0; i < 12; ++i) {
        const int G = i*256 + tid;
        stg[i] = *(const float4*)(wb + (size_t)((ht+1)*32 + G/96) * Dc + (G%96) * 8);
      }
    }

    // K-loop: 24 x (swizzled ds_read_b128 + MFMA)
    f32x4 acc = {0.f, 0.f, 0.f, 0.f};
    const unsigned short* bbase = &Bsb[(cg*16 + fr) * Dc];
    #pragma unroll
    for (int kt = 0; kt < 24; ++kt) {
      const bf16x8 b = *(const bf16x8*)(bbase + (((kt*4 + fq) ^ fr7) << 3));
      acc = __builtin_amdgcn_mfma_f32_16x16x32_bf16(af[kt], b, acc, 0, 0, 0);
    }

    // epilogue: v = logit + gumbel; 16-col slice max; ring-append candidates
    #pragma unroll
    for (int s = 0; s < 2; ++s) {
      #pragma unroll
      for (int r = 0; r < 4; ++r) {
        const float v = acc[r] + gg[s*4 + r];
        float m = v;
        m = fmaxf(m, __shfl_xor(m, 1)); m = fmaxf(m, __shfl_xor(m, 2));
        m = fmaxf(m, __shfl_xor(m, 4)); m = fmaxf(m, __shfl_xor(m, 8));
        const int t = tg*16 + fq*4 + r;
        const float gmr = __int_as_float(gmI[t][s]);   // racy read: sound (<= true max)
        if (v >= fmaxf(gmr, m) - MARGIN) {
          const int p = atomicAdd(&cnt[t][s], 1);
          const int q = p % CAND_MAX;                  // ring: drops OLDEST (lowest records)
          candv[t][s][q] = v;
          candc[t][s][q] = ht*32 + cg*16 + fr;
        }
        if (fr == 0) atomicMax(&gmI[t][s], __float_as_int(m));
      }
    }
  }
  __syncthreads();

  // resolve: 64 (t,s) pairs, 16 per wave; keepers within MARGIN; f64 refine
  for (int q = 0; q < 16; ++q) {
    const int p = wid*16 + q, t = p >> 1, s = p & 1;
    const int cc = min(cnt[t][s], CAND_MAX);
    const float val = (lane < cc) ? candv[t][s][lane] : -1e30f;
    const int   col = (lane < cc) ? candc[t][s][lane] : 0x7FFFFFFF;
    float m = val;
    #pragma unroll
    for (int off = 1; off < 64; off <<= 1) m = fmaxf(m, __shfl_xor(m, off));
    const bool keep = (lane < cc) && (val >= m - MARGIN);
    unsigned long long mask = __ballot(keep);
    int chosen;
    if (__popcll(mask) == 1) {
      chosen = __shfl(col, (int)(__ffsll(mask) - 1));
    } else {
      float best = -1e30f; int bk = 0x7FFFFFFF;
      const float* xr = x + (size_t)(t0 + t) * Dc;
      while (mask) {
        const int ln = (int)(__ffsll(mask) - 1); mask &= mask - 1;
        const int kc = __shfl(col, ln);
        const float* wr = w + (size_t)kc * Dc;
        double a = 0.0;
        for (int d = lane; d < Dc; d += 64) a += (double)xr[d] * (double)wr[d];
        #pragma unroll
        for (int off = 32; off; off >>= 1) a += __shfl_xor(a, off);
        const float ex = (float)a + gumbel[((size_t)(t0 + t) * NSc + s) * Kc + kc];
        if (ex > best || (ex == best && kc < bk)) { best = ex; bk = kc; }
      }
      chosen = bk;
    }
    if (lane == 0) sel[t][s] = chosen;
  }
  __syncthreads();

  // writes: one-hot indices (r1-verbatim pattern) + embedding gathers
  for (int p = 0; p < 64; ++p) {
    const int t = p >> 1, s = p & 1;
    const int idx = sel[t][s];
    float* irow = out_ind + ((size_t)(t0 + t) * NSc + s) * Kc;
    #pragma unroll
    for (int j = 0; j < 8; ++j) {
      const int k0 = j*1024 + tid*4;
      float4 z = {0.f, 0.f, 0.f, 0.f};
      const int d = idx - k0;
      if (d == 0) z.x = 1.0f; else if (d == 1) z.y = 1.0f;
      else if (d == 2) z.z = 1.0f; else if (d == 3) z.w = 1.0f;
      ((float4*)irow)[j*256 + tid] = z;
    }
  }
  for (int q = 0; q < 16; ++q) {
    const int p = wid*16 + q, t = p >> 1, s = p & 1;
    const int idx = sel[t][s];
    const float* er = emb_tab + (size_t)idx * Dc;
    float* eo = out_emb + ((size_t)(t0 + t) * NSc + s) * Dc;
    #pragma unroll
    for (int i = 0; i < 12; ++i) eo[lane + i*64] = er[lane + i*64];
  }
}

extern "C" void kernel_launch(void* const* d_in, const int* in_sizes, int n_in,
                              void* d_out, int out_size, void* d_ws, size_t ws_size,
                              hipStream_t stream) {
  const float* x   = (const float*)d_in[0];
  const float* w   = (const float*)d_in[1];
  const float* emb = (const float*)d_in[2];
  const float* gum = (const float*)d_in[3];

  float* out_emb = (float*)d_out;
  float* out_ind = out_emb + EMB_ELEMS;

  unsigned short* xb = (unsigned short*)d_ws;           // [M][D] bf16 (12.6 MB)
  unsigned short* wb = xb + (size_t)Mc * Dc;            // [K][D] bf16 (12.6 MB)

  const int n4 = (Mc * Dc) / 4;
  k_convert<<<n4 / 256, 256, 0, stream>>>((const float4*)x, (const float4*)w,
                                          (u16x4*)xb, (u16x4*)wb);
  k_fused<<<Mc / TPB, 256, 0, stream>>>(xb, wb, gum, x, w, emb, out_emb, out_ind);
}

// Round 6
// 428.277 us; speedup vs baseline: 6.5186x; 6.5186x over previous
//
#include <hip/hip_runtime.h>
#include <stdint.h>

// Problem constants (fixed by the reference)
#define Bc 4
#define Sc 2048
#define Dc 768
#define Kc 8192
#define NSc 2
#define Mc (Bc*Sc)                      // 8192 tokens
#define EMB_ELEMS ((size_t)Mc*NSc*Dc)   // emb output floats; indices follow

typedef __attribute__((ext_vector_type(8))) __bf16 bf16x8;
typedef __attribute__((ext_vector_type(4))) float f32x4;
typedef __attribute__((ext_vector_type(4))) unsigned short u16x4;

__device__ __forceinline__ unsigned short f2bf(float f){
  unsigned int u = __float_as_uint(f);
  u += 0x7FFFu + ((u >> 16) & 1u);       // round-to-nearest-even
  return (unsigned short)(u >> 16);
}
__device__ __forceinline__ float bf2f(unsigned short h){
  return __uint_as_float(((unsigned int)h) << 16);
}

// ---------------- K0: convert x,w f32 -> bf16 (into ws) ----------------
__global__ __launch_bounds__(256) void k_convert(const float4* __restrict__ x,
                                                 const float4* __restrict__ w,
                                                 u16x4* __restrict__ xb,
                                                 u16x4* __restrict__ wb){
  int i = blockIdx.x * 256 + threadIdx.x;
  float4 v = x[i];
  u16x4 o;
  o.x = f2bf(v.x); o.y = f2bf(v.y); o.z = f2bf(v.z); o.w = f2bf(v.w);
  xb[i] = o;
  v = w[i];
  o.x = f2bf(v.x); o.y = f2bf(v.y); o.z = f2bf(v.z); o.w = f2bf(v.w);
  wb[i] = o;
}

// ---------------- K1: bf16 MFMA GEMM (r1 structure) + in-loop zero stores ----
// Output layout inside out_ind (token row = 65536 B = [t][s][k] f32):
//   [t][0][k]          : one-hot sample 0   -> zeroed HERE (in K-loop)
//   [t][1][k<4096]     : one-hot sample 1 lo -> zeroed HERE (in K-loop)
//   [t][1][k>=4096]    : 16 KB quadrant  -> bf16 logit stash (C-write), select
//                        zeroes it after staging and sets the 1.0s.
// Stash: ushort index t*32768 + 24576 + k.
#define BM 128
#define BN 128
#define BK 32

__global__ __launch_bounds__(256) void k_gemm(const unsigned short* __restrict__ xb,
                                              const unsigned short* __restrict__ wb,
                                              unsigned short* __restrict__ stash,
                                              float* __restrict__ out_ind){
  __shared__ unsigned short As[BM*BK];   // 8 KB, linear (global_load_lds dest)
  __shared__ unsigned short Bs[BN*BK];   // 8 KB

  const int tid  = threadIdx.x;
  const int lane = tid & 63;
  const int wid  = tid >> 6;             // 4 waves, 2x2 -> each owns 64x64 out
  const int wm   = wid >> 1;
  const int wn   = wid & 1;

  // XCD-aware swizzle (4096 blocks, 8 XCDs, 4096%8==0 -> bijective)
  const int bid  = (int)blockIdx.x;
  const int swz  = (bid & 7) * 512 + (bid >> 3);
  const int bm0  = (swz >> 6) * BM;      // token block
  const int bn0  = (swz & 63) * BN;      // code block

  f32x4 acc[4][4] = {};

  const int srow  = tid >> 2;
  const int scole = (tid & 3) * 8;
  const unsigned short* aS0 = xb + (size_t)(bm0 + srow) * Dc + scole;
  const unsigned short* aS1 = xb + (size_t)(bm0 + 64 + srow) * Dc + scole;
  const unsigned short* bS0 = wb + (size_t)(bn0 + srow) * Dc + scole;
  const unsigned short* bS1 = wb + (size_t)(bn0 + 64 + srow) * Dc + scole;
  unsigned short* aD0 = &As[wid * 512];
  unsigned short* aD1 = &As[2048 + wid * 512];
  unsigned short* bD0 = &Bs[wid * 512];
  unsigned short* bD1 = &Bs[2048 + wid * 512];

  const int fr = lane & 15;
  const int fk = (lane >> 4) * 8;

  for (int it = 0; it < Dc/BK; ++it) {   // 24 iterations
    __syncthreads();
    const int kt = it * BK;
    __builtin_amdgcn_global_load_lds((const __attribute__((address_space(1))) void*)(aS0 + kt),
                                     (__attribute__((address_space(3))) void*)aD0, 16, 0, 0);
    __builtin_amdgcn_global_load_lds((const __attribute__((address_space(1))) void*)(aS1 + kt),
                                     (__attribute__((address_space(3))) void*)aD1, 16, 0, 0);
    __builtin_amdgcn_global_load_lds((const __attribute__((address_space(1))) void*)(bS0 + kt),
                                     (__attribute__((address_space(3))) void*)bD0, 16, 0, 0);
    __builtin_amdgcn_global_load_lds((const __attribute__((address_space(1))) void*)(bS1 + kt),
                                     (__attribute__((address_space(3))) void*)bD1, 16, 0, 0);

    // in-loop one-hot zero stores (independent of everything; rides idle HBM)
    if (it < 16) {
      const int n  = it*256 + tid;       // 4096 float4s per sample region
      const int tl = n >> 5, f4 = n & 31;
      float4 z = {0.f, 0.f, 0.f, 0.f};
      float4* zp = (float4*)out_ind + (size_t)(bm0 + tl)*4096 + (bn0 >> 2) + f4;
      zp[0] = z;                          // [t][0][bn0..bn0+128)
      if (bn0 < 4096) zp[2048] = z;       // [t][1][bn0..bn0+128)  (k<4096 half)
    }
    __syncthreads();

    bf16x8 a[4], b[4];
    #pragma unroll
    for (int i = 0; i < 4; i++) {
      a[i] = *(const bf16x8*)&As[(wm*64 + i*16 + fr) * BK + fk];
      b[i] = *(const bf16x8*)&Bs[(wn*64 + i*16 + fr) * BK + fk];
    }
    #pragma unroll
    for (int i = 0; i < 4; i++)
      #pragma unroll
      for (int j = 0; j < 4; j++)
        acc[i][j] = __builtin_amdgcn_mfma_f32_16x16x32_bf16(a[i], b[j], acc[i][j], 0, 0, 0);
  }

  // C-write to stash. C/D layout: col = lane&15, row = (lane>>4)*4 + reg
  const int crow0 = bm0 + wm*64 + (lane >> 4) * 4;
  const int ccol0 = bn0 + wn*64 + (lane & 15);
  #pragma unroll
  for (int i = 0; i < 4; i++)
    #pragma unroll
    for (int j = 0; j < 4; j++)
      #pragma unroll
      for (int r = 0; r < 4; r++)
        stash[(size_t)(crow0 + i*16 + r) * 32768 + (ccol0 + j*16)] = f2bf(acc[i][j][r]);
}

// ---------------- K2: select (r1 logic) + lean writes -----------------------
#define MARGIN 0.125f

__global__ __launch_bounds__(256) void k_select(const unsigned short* stash,    // aliases out_ind!
                                                const float* __restrict__ gumbel,
                                                const float* __restrict__ x,
                                                const float* __restrict__ w,
                                                const float* __restrict__ emb_tab,
                                                float* __restrict__ out_emb,
                                                float* out_ind){
  const int t   = blockIdx.x;
  const int tid = threadIdx.x;
  const int lane = tid & 63, wid = tid >> 6;

  __shared__ unsigned short Lrow[Kc];    // 16 KB bf16 logits row
  __shared__ float wmax[4];
  __shared__ int   cand_k[16];
  __shared__ float cand_g[16];
  __shared__ int   cand_cnt;
  __shared__ int   sel_idx[NSc];

  // stage logits row t into LDS (stash quadrant gets overwritten below)
  {
    const u16x4* src = (const u16x4*)(stash + (size_t)t * 32768);
    u16x4* dst = (u16x4*)Lrow;
    #pragma unroll
    for (int j = 0; j < 8; j++) dst[j*256 + tid] = src[j*256 + tid];
  }
  __syncthreads();

  for (int s = 0; s < NSc; ++s) {
    const float* grow = gumbel + ((size_t)t * NSc + s) * Kc;
    float4 vals[8];
    float m = -1e30f;
    #pragma unroll
    for (int j = 0; j < 8; j++) {
      float4 g4 = ((const float4*)grow)[j*256 + tid];
      u16x4 l4 = *(const u16x4*)&Lrow[j*1024 + tid*4];
      float4 v;
      v.x = bf2f(l4.x) + g4.x;
      v.y = bf2f(l4.y) + g4.y;
      v.z = bf2f(l4.z) + g4.z;
      v.w = bf2f(l4.w) + g4.w;
      vals[j] = v;
      m = fmaxf(m, fmaxf(fmaxf(v.x, v.y), fmaxf(v.z, v.w)));
    }
    #pragma unroll
    for (int off = 32; off; off >>= 1) m = fmaxf(m, __shfl_xor(m, off));
    if (lane == 0) wmax[wid] = m;
    __syncthreads();
    const float gmax = fmaxf(fmaxf(wmax[0], wmax[1]), fmaxf(wmax[2], wmax[3]));
    if (tid == 0) cand_cnt = 0;
    __syncthreads();

    const float thr = gmax - MARGIN;
    #pragma unroll
    for (int j = 0; j < 8; j++) {
      const int k0 = j*1024 + tid*4;
      float vv[4] = {vals[j].x, vals[j].y, vals[j].z, vals[j].w};
      #pragma unroll
      for (int q = 0; q < 4; q++) {
        if (vv[q] >= thr) {
          int p = atomicAdd(&cand_cnt, 1);
          if (p < 16) cand_k[p] = k0 + q;
        }
      }
    }
    __syncthreads();

    const int cnt = min(cand_cnt, 16);
    if (cnt == 1) {
      if (tid == 0) sel_idx[s] = cand_k[0];
    } else {
      // exact refine: wave `wid` takes candidates wid, wid+4, ...
      for (int c = wid; c < cnt; c += 4) {
        const int kc = cand_k[c];
        const float* wr = w + (size_t)kc * Dc;
        const float* xr = x + (size_t)t * Dc;
        double accd = 0.0;
        for (int d = lane; d < Dc; d += 64) accd += (double)xr[d] * (double)wr[d];
        #pragma unroll
        for (int off = 32; off; off >>= 1) accd += __shfl_xor(accd, off);
        if (lane == 0) cand_g[c] = (float)accd + grow[kc];
      }
      __syncthreads();
      if (tid == 0) {
        float bg = -1e30f; int bk = Kc;
        for (int c = 0; c < cnt; ++c) {
          const float gg = cand_g[c]; const int kk = cand_k[c];
          if (gg > bg || (gg == bg && kk < bk)) { bg = gg; bk = kk; }
        }
        sel_idx[s] = bk;
      }
    }
    __syncthreads();
  }

  // ---- lean writes: zero the stash quadrant [t][1][k>=4096], then the 1.0s.
  // Everything else was pre-zeroed by k_gemm.
  {
    float* row1hi = out_ind + (size_t)t*16384 + 8192 + 4096;
    float4 z = {0.f, 0.f, 0.f, 0.f};
    #pragma unroll
    for (int q = 0; q < 4; ++q)
      ((float4*)row1hi)[q*256 + tid] = z;
  }
  __syncthreads();                        // zero stores complete before the 1.0s
  if (tid == 0) {
    out_ind[(size_t)t*16384 +        sel_idx[0]] = 1.0f;
    out_ind[(size_t)t*16384 + 8192 + sel_idx[1]] = 1.0f;
  }

  // embedding gathers
  #pragma unroll
  for (int s = 0; s < NSc; ++s) {
    const int idx = sel_idx[s];
    const float* er = emb_tab + (size_t)idx * Dc;
    float* eo = out_emb + ((size_t)t*NSc + s)*Dc;
    for (int d = tid; d < Dc; d += 256) eo[d] = er[d];
  }
}

extern "C" void kernel_launch(void* const* d_in, const int* in_sizes, int n_in,
                              void* d_out, int out_size, void* d_ws, size_t ws_size,
                              hipStream_t stream) {
  const float* x   = (const float*)d_in[0];
  const float* w   = (const float*)d_in[1];
  const float* emb = (const float*)d_in[2];
  const float* gum = (const float*)d_in[3];

  float* out_emb = (float*)d_out;
  float* out_ind = out_emb + EMB_ELEMS;
  // bf16 logit stash: [t][1][k>=4096] quadrant == ushort index t*32768 + 24576
  unsigned short* stash = (unsigned short*)out_ind + 24576;

  unsigned short* xb = (unsigned short*)d_ws;           // [M][D] bf16 (12.6 MB)
  unsigned short* wb = xb + (size_t)Mc * Dc;            // [K][D] bf16 (12.6 MB)

  const int n4 = (Mc * Dc) / 4;
  k_convert<<<n4 / 256, 256, 0, stream>>>((const float4*)x, (const float4*)w,
                                          (u16x4*)xb, (u16x4*)wb);
  k_gemm<<<4096, 256, 0, stream>>>(xb, wb, stash, out_ind);
  k_select<<<Mc, 256, 0, stream>>>(stash, gum, x, w, emb, out_emb, out_ind);
}